// Round 12
// baseline (130.976 us; speedup 1.0000x reference)
//
#include <hip/hip_runtime.h>
#include <hip/hip_bf16.h>
#include <math.h>

// CausalFullAttention: out[b,l,h,d] = softmax_s( 0.125*(q.k + bias[l,s]), s<=l ) @ V
// B=4 L=S=2048 H=8 E=D=64, fp32 in/out, bf16 MFMA compute.
// R11: 32x32x16 MFMA restructure (m214 recipe). QBLK=32/wave, 4 waves x 256 threads,
//      swapped QK^T -> lane owns a full 64-kv slice of one q-row (split across lane
//      halves); softmax = 31 in-lane + 1 shfl; P re-frag = 16 pack + 8 shfl + selects.
//      Shell (T14 staging, dbuf, pairing, 512 blocks) unchanged.

typedef __bf16 bf16x8 __attribute__((ext_vector_type(8)));
typedef __bf16 bf16x4 __attribute__((ext_vector_type(4)));
typedef __bf16 bf16x2 __attribute__((ext_vector_type(2)));
typedef float  f32x16 __attribute__((ext_vector_type(16)));
typedef unsigned int u32;
typedef u32 u32x4 __attribute__((ext_vector_type(4)));

#define NB 4
#define NL 2048
#define NS 2048
#define NH 8
#define NE 64
#define ND 64

__device__ __forceinline__ int swz(int d) { return ((d ^ (d >> 3)) & 7) << 3; }

__device__ __forceinline__ u32 pack2(float lo, float hi) {
    bf16x2 t; t[0] = (__bf16)lo; t[1] = (__bf16)hi;
    return __builtin_bit_cast(u32, t);
}
__device__ __forceinline__ float unplo(u32 u) { return __uint_as_float(u << 16); }
__device__ __forceinline__ float unphi(u32 u) { return __uint_as_float(u & 0xffff0000u); }
__device__ __forceinline__ u32 sx32(u32 v) { return (u32)__shfl_xor((int)v, 32, 64); }
__device__ __forceinline__ float bpermf(int srclane, float v) {
    return __uint_as_float((u32)__builtin_amdgcn_ds_bpermute(srclane << 2, (int)__float_as_uint(v)));
}

__device__ __forceinline__ bf16x8 cvt8s(float4 a, float4 b, float sc) {
    bf16x8 r;
    r[0]=(__bf16)(a.x*sc); r[1]=(__bf16)(a.y*sc); r[2]=(__bf16)(a.z*sc); r[3]=(__bf16)(a.w*sc);
    r[4]=(__bf16)(b.x*sc); r[5]=(__bf16)(b.y*sc); r[6]=(__bf16)(b.z*sc); r[7]=(__bf16)(b.w*sc);
    return r;
}
__device__ __forceinline__ bf16x8 cvt8(float4 a, float4 b) {
    bf16x8 r;
    r[0]=(__bf16)a.x; r[1]=(__bf16)a.y; r[2]=(__bf16)a.z; r[3]=(__bf16)a.w;
    r[4]=(__bf16)b.x; r[5]=(__bf16)b.y; r[6]=(__bf16)b.z; r[7]=(__bf16)b.w;
    return r;
}

__global__ __launch_bounds__(256)
void fa_fwd(const float* __restrict__ Q, const float* __restrict__ K,
            const float* __restrict__ V, const float* __restrict__ Bias,
            float* __restrict__ Out)
{
    __shared__ __bf16 Klds[2][64][72];   // K tile [kv][e], +8 pad
    __shared__ __bf16 Vlds[2][64][64];   // V^T tile [d][kv], XOR slot swizzle

    const int tid = threadIdx.x;
    const int w   = tid >> 6, lane = tid & 63;
    const int l31 = lane & 31, hf = lane >> 5;

    // 512 blocks (2/CU); complementary heavy/light pairing.
    const int id = blockIdx.x;
    int bh, qp_;
    if (id < 256) { bh = id >> 4;                qp_ = 15 - (id & 15); }
    else          { bh = 16 + ((id - 256) >> 4); qp_ = id & 15;        }
    const int b  = bh >> 3, hh = bh & 7;
    const int qb = qp_ << 7;
    const int qw = qb + (w << 5);          // this wave's first q row (32 rows)

    const float SC = 0.125f * 1.44269504088896340736f;  // scale * log2(e)

    // Q B-frags: lane holds Q[qw+l31][e = 16*sub + 8*hf + j], pre-scaled
    bf16x8 qf[4];
    {
        const float* qp = Q + (((size_t)(b * NL + qw + l31)) * NH + hh) * NE;
        #pragma unroll
        for (int sub = 0; sub < 4; ++sub) {
            const int e0 = 16 * sub + 8 * hf;
            float4 f0 = *(const float4*)(qp + e0);
            float4 f1 = *(const float4*)(qp + e0 + 4);
            qf[sub] = cvt8s(f0, f1, SC);
        }
    }

    f32x16 o0 = {}, o1 = {};               // O rows q=crow(r,hf), cols d=l31 / 32+l31
    float m_run = -INFINITY, l_run = 0.0f; // per-lane, q = l31 row of this wave

    const int ntiles = (qb >> 6) + 2;

    // staging indices (256 threads)
    const int skv = tid >> 2,        se0 = (tid & 3) << 4;   // K: row, 16-float chunk
    const int vkv = (tid >> 4) << 2, vd0 = (tid & 15) << 2;  // V: 4kv x 4d sub-block

    const float* kp0 = K + (((size_t)(b * NS + skv)) * NH + hh) * NE + se0;
    const float* vp0 = V + (((size_t)(b * NS + vkv)) * NH + hh) * ND + vd0;
    const float* bp0 = Bias + (size_t)(qw + l31) * NS + 4 * hf;

    float4 ka0, ka1, ka2, ka3, va0, va1, va2, va3;   // stage regs
    u32 bc0[8], bc1[8], bn0[8], bn1[8];              // bias bf16-packed: [rr*2+p], ct=0/1

    auto issue_kv = [&](int T) {
        const float* kp = kp0 + (size_t)(T << 6) * (NH * NE);
        ka0 = ((const float4*)kp)[0]; ka1 = ((const float4*)kp)[1];
        ka2 = ((const float4*)kp)[2]; ka3 = ((const float4*)kp)[3];
        const float* vp = vp0 + (size_t)(T << 6) * (NH * ND);
        va0 = *(const float4*)(vp);
        va1 = *(const float4*)(vp + NH * ND);
        va2 = *(const float4*)(vp + 2 * NH * ND);
        va3 = *(const float4*)(vp + 3 * NH * ND);
    };
    auto load_bias = [&](u32 (&b0)[8], u32 (&b1)[8], int T) {
        const float* bp = bp0 + (T << 6);
        #pragma unroll
        for (int rr = 0; rr < 4; ++rr) {
            float4 f = *(const float4*)(bp + 8 * rr);
            b0[rr * 2]     = pack2(f.x, f.y);
            b0[rr * 2 + 1] = pack2(f.z, f.w);
            float4 g = *(const float4*)(bp + 32 + 8 * rr);
            b1[rr * 2]     = pack2(g.x, g.y);
            b1[rr * 2 + 1] = pack2(g.z, g.w);
        }
    };
    auto write_lds = [&](int buf) {
        *(bf16x8*)&Klds[buf][skv][se0]     = cvt8(ka0, ka1);
        *(bf16x8*)&Klds[buf][skv][se0 + 8] = cvt8(ka2, ka3);
        bf16x4 cc;
        cc[0]=(__bf16)va0.x; cc[1]=(__bf16)va1.x; cc[2]=(__bf16)va2.x; cc[3]=(__bf16)va3.x;
        *(bf16x4*)&Vlds[buf][vd0 + 0][vkv ^ swz(vd0 + 0)] = cc;
        cc[0]=(__bf16)va0.y; cc[1]=(__bf16)va1.y; cc[2]=(__bf16)va2.y; cc[3]=(__bf16)va3.y;
        *(bf16x4*)&Vlds[buf][vd0 + 1][vkv ^ swz(vd0 + 1)] = cc;
        cc[0]=(__bf16)va0.z; cc[1]=(__bf16)va1.z; cc[2]=(__bf16)va2.z; cc[3]=(__bf16)va3.z;
        *(bf16x4*)&Vlds[buf][vd0 + 2][vkv ^ swz(vd0 + 2)] = cc;
        cc[0]=(__bf16)va0.w; cc[1]=(__bf16)va1.w; cc[2]=(__bf16)va2.w; cc[3]=(__bf16)va3.w;
        *(bf16x4*)&Vlds[buf][vd0 + 3][vkv ^ swz(vd0 + 3)] = cc;
    };

    // ---- prologue ----
    issue_kv(0);
    load_bias(bc0, bc1, 0);
    write_lds(0);
    __syncthreads();

    for (int t = 0; t < ntiles; ++t) {
        const int cur = t & 1;
        const bool more = (t + 1 < ntiles);

        if (more) { issue_kv(t + 1); load_bias(bn0, bn1, t + 1); }

        const int kv0 = t << 6;
        if (kv0 <= qw + 31) {              // wave-uniform causal skip
            // swapped QK^T: s0/s1 = S[kv(ct tile)][q=l31], lane kv = 32ct+crow(r,hf)
            f32x16 s0 = {}, s1 = {};
            #pragma unroll
            for (int sub = 0; sub < 4; ++sub) {
                bf16x8 k0 = *(const bf16x8*)&Klds[cur][l31][16 * sub + 8 * hf];
                bf16x8 k1 = *(const bf16x8*)&Klds[cur][32 + l31][16 * sub + 8 * hf];
                s0 = __builtin_amdgcn_mfma_f32_32x32x16_bf16(k0, qf[sub], s0, 0, 0, 0);
                s1 = __builtin_amdgcn_mfma_f32_32x32x16_bf16(k1, qf[sub], s1, 0, 0, 0);
            }
            const int lg = qw + l31;
            if (kv0 + 63 > qw) {           // straddle: bias + causal select
                #pragma unroll
                for (int rr = 0; rr < 4; ++rr)
                    #pragma unroll
                    for (int p = 0; p < 2; ++p) {
                        const int i = 4 * rr + 2 * p;
                        const int kvb = kv0 + 8 * rr + 4 * hf + 2 * p;
                        const u32 u0 = bc0[rr * 2 + p], u1 = bc1[rr * 2 + p];
                        s0[i]   = (kvb      <= lg) ? fmaf(unplo(u0), SC, s0[i])   : -INFINITY;
                        s0[i+1] = (kvb + 1  <= lg) ? fmaf(unphi(u0), SC, s0[i+1]) : -INFINITY;
                        s1[i]   = (kvb + 32 <= lg) ? fmaf(unplo(u1), SC, s1[i])   : -INFINITY;
                        s1[i+1] = (kvb + 33 <= lg) ? fmaf(unphi(u1), SC, s1[i+1]) : -INFINITY;
                    }
            } else {
                #pragma unroll
                for (int rr = 0; rr < 4; ++rr)
                    #pragma unroll
                    for (int p = 0; p < 2; ++p) {
                        const int i = 4 * rr + 2 * p;
                        const u32 u0 = bc0[rr * 2 + p], u1 = bc1[rr * 2 + p];
                        s0[i]   = fmaf(unplo(u0), SC, s0[i]);
                        s0[i+1] = fmaf(unphi(u0), SC, s0[i+1]);
                        s1[i]   = fmaf(unplo(u1), SC, s1[i]);
                        s1[i+1] = fmaf(unphi(u1), SC, s1[i+1]);
                    }
            }
            // row max: 31 in-lane + 1 cross-half shuffle
            float pm = s0[0];
            #pragma unroll
            for (int i = 1; i < 16; ++i) pm = fmaxf(pm, s0[i]);
            #pragma unroll
            for (int i = 0; i < 16; ++i) pm = fmaxf(pm, s1[i]);
            pm = fmaxf(pm, __shfl_xor(pm, 32, 64));
            // defer-max (T13)
            if (!__all(pm <= m_run + 8.0f)) {
                const float mn = fmaxf(m_run, pm);
                const float corr = exp2f(m_run - mn);
                m_run = mn; l_run *= corr;
                #pragma unroll
                for (int r = 0; r < 16; ++r) {
                    const float cj = bpermf((r & 3) + 8 * (r >> 2) + 4 * hf, corr);
                    o0[r] *= cj; o1[r] *= cj;
                }
            }
            #pragma unroll
            for (int i = 0; i < 16; ++i) s0[i] = exp2f(s0[i] - m_run);
            #pragma unroll
            for (int i = 0; i < 16; ++i) s1[i] = exp2f(s1[i] - m_run);
            float rs = 0.0f;
            #pragma unroll
            for (int i = 0; i < 16; ++i) rs += s0[i] + s1[i];
            rs += __shfl_xor(rs, 32, 64);
            l_run += rs;
            // P re-frag: pack pairs, one cross-half exchange per (ks,half-word)
            u32 wv[4][2][2];
            #pragma unroll
            for (int ks = 0; ks < 4; ++ks)
                #pragma unroll
                for (int hd = 0; hd < 2; ++hd) {
                    const int base = 4 * (2 * (ks & 1) + hd);
                    if (ks < 2) {
                        wv[ks][hd][0] = pack2(s0[base],     s0[base + 1]);
                        wv[ks][hd][1] = pack2(s0[base + 2], s0[base + 3]);
                    } else {
                        wv[ks][hd][0] = pack2(s1[base],     s1[base + 1]);
                        wv[ks][hd][1] = pack2(s1[base + 2], s1[base + 3]);
                    }
                }
            const bool hb = (hf != 0);
            u32x4 pad[4];
            #pragma unroll
            for (int ks = 0; ks < 4; ++ks) {
                const u32 send0 = hb ? wv[ks][0][0] : wv[ks][1][0];
                const u32 send1 = hb ? wv[ks][0][1] : wv[ks][1][1];
                const u32 r0 = sx32(send0), r1 = sx32(send1);
                pad[ks][0] = hb ? r0 : wv[ks][0][0];
                pad[ks][1] = hb ? r1 : wv[ks][0][1];
                pad[ks][2] = hb ? wv[ks][1][0] : r0;
                pad[ks][3] = hb ? wv[ks][1][1] : r1;
            }
            // PV: O += P @ V, k-slots ks=0..3
            #pragma unroll
            for (int ks = 0; ks < 4; ++ks) {
                const bf16x8 pa = __builtin_bit_cast(bf16x8, pad[ks]);
                bf16x8 v0 = *(const bf16x8*)&Vlds[cur][l31][(16 * ks + 8 * hf) ^ swz(l31)];
                bf16x8 v1 = *(const bf16x8*)&Vlds[cur][32 + l31][(16 * ks + 8 * hf) ^ swz(32 + l31)];
                o0 = __builtin_amdgcn_mfma_f32_32x32x16_bf16(pa, v0, o0, 0, 0, 0);
                o1 = __builtin_amdgcn_mfma_f32_32x32x16_bf16(pa, v1, o1, 0, 0, 0);
            }
        }

        if (more) {
            __syncthreads();
            write_lds(cur ^ 1);
            __syncthreads();
            #pragma unroll
            for (int i = 0; i < 8; ++i) { bc0[i] = bn0[i]; bc1[i] = bn1[i]; }
        }
    }

    // ---- epilogue: transport l to O layout, normalize, store ----
    #pragma unroll
    for (int r = 0; r < 16; ++r) {
        const int crow = (r & 3) + 8 * (r >> 2) + 4 * hf;
        const float lj = bpermf(crow, l_run);
        const float inv = 1.0f / lj;
        float* op = Out + (((size_t)(b * NL + qw + crow)) * NH + hh) * ND + l31;
        op[0]  = o0[r] * inv;
        op[32] = o1[r] * inv;
    }
}

extern "C" void kernel_launch(void* const* d_in, const int* in_sizes, int n_in,
                              void* d_out, int out_size, void* d_ws, size_t ws_size,
                              hipStream_t stream)
{
    const float* Q    = (const float*)d_in[0];
    const float* K    = (const float*)d_in[1];
    const float* V    = (const float*)d_in[2];
    const float* Bias = (const float*)d_in[3];
    // d_in[4] (attn_mask) is the static triu(k=1) causal mask - handled analytically.
    float* Out = (float*)d_out;
    dim3 grid(NL / 128 * NB * NH);   // 512 blocks, remapped in-kernel
    dim3 block(256);
    fa_fwd<<<grid, block, 0, stream>>>(Q, K, V, Bias, Out);
}